// Round 6
// baseline (269.203 us; speedup 1.0000x reference)
//
#include <hip/hip_runtime.h>
#include <hip/hip_bf16.h>

#define B_ 8
#define N_ 1024
#define DIN 256
#define DOUT 256
#define R_ 4

typedef __attribute__((ext_vector_type(8))) short bf16x8;
typedef __attribute__((ext_vector_type(4))) float f32x4;
typedef __attribute__((ext_vector_type(4))) int i32x4;

__device__ __forceinline__ unsigned short f2bf(float f) {
    union { float f; unsigned int u; } v; v.f = f;
    unsigned int u = v.u;
    u += 0x7fffu + ((u >> 16) & 1u);
    return (unsigned short)(u >> 16);
}
__device__ __forceinline__ float bf2f(unsigned short h) {
    union { float f; unsigned int u; } v; v.u = ((unsigned int)h) << 16;
    return v.f;
}

// async global->LDS, 16B/lane. LDS dest = wave-uniform base + lane*16.
__device__ __forceinline__ void gl_lds16(const void* g, void* l) {
    __builtin_amdgcn_global_load_lds(
        (const __attribute__((address_space(1))) unsigned int*)g,
        (__attribute__((address_space(3))) unsigned int*)l, 16, 0, 0);
}

#define WAIT_VM0   0x3F70  // vmcnt(0), expcnt/lgkmcnt = no-wait
#define WAIT_LGKM0 0xC07F  // lgkmcnt(0), vmcnt/expcnt = no-wait

// ---- k0: swizzle rel_w (f32 [R][D][K]) into bf16 MFMA B-fragment layout ----
__global__ __launch_bounds__(256) void k0_swz(const float* __restrict__ rw,
                                              unsigned short* __restrict__ swzW) {
    int t = blockIdx.x * 256 + threadIdx.x;  // 0..32767
    int lane = t & 63, nb = (t >> 6) & 15, ks = (t >> 10) & 7, r = t >> 13;
    int m = lane & 15, q = lane >> 4;
    const float* src = rw + ((r * DOUT + nb * 16 + m) * DIN) + ks * 32 + q * 8;
    float4 v0 = *(const float4*)src;
    float4 v1 = *(const float4*)(src + 4);
    bf16x8 o;
    o[0] = (short)f2bf(v0.x); o[1] = (short)f2bf(v0.y);
    o[2] = (short)f2bf(v0.z); o[3] = (short)f2bf(v0.w);
    o[4] = (short)f2bf(v1.x); o[5] = (short)f2bf(v1.y);
    o[6] = (short)f2bf(v1.z); o[7] = (short)f2bf(v1.w);
    *(bf16x8*)(swzW + (long)t * 8) = o;
}

// ---- k1: G[j][d] = e[j]*(node@rel_w^T + rel_b)[j][d], B-fragment layout -----
__global__ __launch_bounds__(256) void k1_proj(const float* __restrict__ node,
        const unsigned short* __restrict__ swzW, const float* __restrict__ rel_b,
        const float* __restrict__ attn_w,
        unsigned short* __restrict__ fswz, unsigned short* __restrict__ ebf) {
    __shared__ unsigned short Wbuf[2][8192];
    int bid = blockIdx.x;
    int nt = bid & 15, r = (bid >> 4) & 3, b = bid >> 6;
    int w = threadIdx.x >> 6, lane = threadIdx.x & 63;
    int m = lane & 15, q = lane >> 4;
    int n0 = nt * 64 + w * 16;

    const float* Abase = node + ((b * N_ + n0 + m) * DIN) + q * 8;
    const unsigned short* Wsrc = swzW + r * 65536;

#pragma unroll
    for (int i = 0; i < 4; i++)
        gl_lds16(Wsrc + (w * 4 + i) * 512 + lane * 8, &Wbuf[0][(w * 4 + i) * 512]);

    f32x4 acc[16];
#pragma unroll
    for (int i = 0; i < 16; i++) acc[i] = (f32x4)0.0f;

    float4 a0 = *(const float4*)(Abase);
    float4 a1 = *(const float4*)(Abase + 4);

    for (int ks = 0; ks < 8; ks++) {
        int cur = ks & 1;
        __syncthreads();
        if (ks < 7) {
#pragma unroll
            for (int i = 0; i < 4; i++)
                gl_lds16(Wsrc + ((ks + 1) * 16 + w * 4 + i) * 512 + lane * 8,
                         &Wbuf[cur ^ 1][(w * 4 + i) * 512]);
        }
        bf16x8 af;
        af[0] = (short)f2bf(a0.x); af[1] = (short)f2bf(a0.y);
        af[2] = (short)f2bf(a0.z); af[3] = (short)f2bf(a0.w);
        af[4] = (short)f2bf(a1.x); af[5] = (short)f2bf(a1.y);
        af[6] = (short)f2bf(a1.z); af[7] = (short)f2bf(a1.w);
        if (ks < 7) {
            a0 = *(const float4*)(Abase + (ks + 1) * 32);
            a1 = *(const float4*)(Abase + (ks + 1) * 32 + 4);
        }
#pragma unroll
        for (int nb = 0; nb < 16; nb++) {
            bf16x8 wf = *(const bf16x8*)(&Wbuf[cur][nb * 512 + lane * 8]);
            acc[nb] = __builtin_amdgcn_mfma_f32_16x16x32_bf16(af, wf, acc[nb], 0, 0, 0);
        }
    }

    float sj0 = 0.f, sj1 = 0.f, sj2 = 0.f, sj3 = 0.f;
    float bias[16], aw[16];
#pragma unroll
    for (int nb = 0; nb < 16; nb++) {
        int d = nb * 16 + m;
        bias[nb] = rel_b[r * DOUT + d];
        aw[nb] = attn_w[DOUT + d];
        sj0 += (acc[nb][0] + bias[nb]) * aw[nb];
        sj1 += (acc[nb][1] + bias[nb]) * aw[nb];
        sj2 += (acc[nb][2] + bias[nb]) * aw[nb];
        sj3 += (acc[nb][3] + bias[nb]) * aw[nb];
    }
#pragma unroll
    for (int mk = 1; mk <= 8; mk <<= 1) {
        sj0 += __shfl_xor(sj0, mk, 64);
        sj1 += __shfl_xor(sj1, mk, 64);
        sj2 += __shfl_xor(sj2, mk, 64);
        sj3 += __shfl_xor(sj3, mk, 64);
    }
    float e0 = __expf(sj0), e1 = __expf(sj1), e2 = __expf(sj2), e3 = __expf(sj3);

    int slice = b * R_ + r;
    int js = n0 >> 5;
    int jhi = (n0 >> 4) & 1;
    int qp = jhi * 2 + (q >> 1);
    int jj0 = (q & 1) * 4;
    unsigned short* fb = fswz + ((long)(slice * 32 + js) * 16) * 512
                       + qp * 128 + m * 8 + jj0;
#pragma unroll
    for (int nb = 0; nb < 16; nb++) {
        ushort4 o;
        o.x = f2bf((acc[nb][0] + bias[nb]) * e0);
        o.y = f2bf((acc[nb][1] + bias[nb]) * e1);
        o.z = f2bf((acc[nb][2] + bias[nb]) * e2);
        o.w = f2bf((acc[nb][3] + bias[nb]) * e3);
        *(ushort4*)(fb + nb * 512) = o;
    }
    if (m == 0) {
        ushort4 o;
        o.x = f2bf(e0); o.y = f2bf(e1); o.z = f2bf(e2); o.w = f2bf(e3);
        *(ushort4*)(ebf + slice * N_ + n0 + q * 4) = o;
    }
}

// ---- k3: accU = A @ G over a j-half + partial l, PRODUCER-CONSUMER ----------
// 5 waves: wave 4 streams G through a 3-deep LDS ring (global_load_lds +
// vmcnt(0) + release flag); waves 0-3 spin on flag, MFMA, signal via ds_add.
// NO __syncthreads in the K-loop -> no whole-CU vmcnt(0) drains.
// grid 1024 = slice(32) x it(16) x jh(2); 50KB LDS -> 3 blocks/CU.
__global__ __launch_bounds__(320, 4) void k3_attn(const int* __restrict__ adj,
        const unsigned short* __restrict__ fswz, const unsigned short* __restrict__ ebf,
        unsigned short* __restrict__ aggU, float* __restrict__ lbuf) {
    __shared__ unsigned short Gbuf[3][8192];  // 3 x 16KB ring
    __shared__ unsigned short Ebuf[512];      // 1KB: this j-half's e
    __shared__ int vflag[3];                  // buffer b holds step (vflag[b]-1)
    __shared__ int vcons[3];                  // consumers done with buffer b

    int bid = blockIdx.x;
    int slice = (bid & 7) * 4 + ((bid >> 3) & 3);  // XCD-affine slice grouping
    int rest = bid >> 5;
    int it = rest & 15, jh = rest >> 4;
    int t = threadIdx.x, lane = t & 63, w = t >> 6;
    int m = lane & 15, q = lane >> 4;
    int i0b = it * 64;

    const unsigned short* fsl = fswz + ((size_t)(slice * 32 + jh * 16)) * 8192;
    const unsigned short* esl = ebf + slice * N_ + jh * 512;

    if (t < 3) { vflag[t] = 0; vcons[t] = 0; }
    __syncthreads();  // the only barrier: flag init

    if (w == 4) {
        // ---------------- producer wave ----------------
        gl_lds16(esl + lane * 8, &Ebuf[0]);
#pragma unroll 1
        for (int s = 0; s < 3; s++) {
            const unsigned short* src = fsl + (size_t)s * 8192;
#pragma unroll
            for (int i = 0; i < 16; i++)
                gl_lds16(src + i * 512 + lane * 8, &Gbuf[s][i * 512]);
            __builtin_amdgcn_s_waitcnt(WAIT_VM0);
            if (lane == 0) ((volatile int*)vflag)[s] = s + 1;
        }
#pragma unroll 1
        for (int s = 3; s < 16; s++) {
            int b3 = s % 3;
            while (((volatile int*)vcons)[b3] < 4) { }
            __builtin_amdgcn_s_waitcnt(WAIT_LGKM0);
            if (lane == 0) ((volatile int*)vcons)[b3] = 0;
            const unsigned short* src = fsl + (size_t)s * 8192;
#pragma unroll
            for (int i = 0; i < 16; i++)
                gl_lds16(src + i * 512 + lane * 8, &Gbuf[b3][i * 512]);
            __builtin_amdgcn_s_waitcnt(WAIT_VM0);
            if (lane == 0) ((volatile int*)vflag)[b3] = s + 1;
        }
        return;
    }

    // ---------------- consumer waves (0-3) ----------------
    const int* adjbase = adj + (size_t)slice * (N_ * N_)
                       + (size_t)(i0b + w * 16 + m) * N_ + jh * 512 + q * 8;

    i32x4 A0c = *(const i32x4*)(adjbase);
    i32x4 A1c = *(const i32x4*)(adjbase + 4);

    f32x4 acc[16];
#pragma unroll
    for (int i = 0; i < 16; i++) acc[i] = (f32x4)0.0f;
    float l = 0.f;

#pragma unroll 1
    for (int s = 0; s < 16; s++) {
        int b3 = s % 3;
        i32x4 A0n, A1n;
        if (s < 15) {  // prefetch next adj before waiting
            A0n = *(const i32x4*)(adjbase + (s + 1) * 32);
            A1n = *(const i32x4*)(adjbase + (s + 1) * 32 + 4);
        }
        while (((volatile int*)vflag)[b3] < s + 1) { }

        bf16x8 ev = *(const bf16x8*)(&Ebuf[s * 32 + q * 8]);
        int av[8] = {A0c.x, A0c.y, A0c.z, A0c.w, A1c.x, A1c.y, A1c.z, A1c.w};
        const int* ei = (const int*)&ev;
        bf16x8 af;
        int* afi = (int*)&af;
#pragma unroll
        for (int p = 0; p < 4; p++) {
            unsigned int msk = (av[2 * p] ? 0xffffu : 0u)
                             | (av[2 * p + 1] ? 0xffff0000u : 0u);
            afi[p] = (int)(msk & 0x3F803F80u);  // A entries: bf16 1.0 / 0.0
            int me = ei[p] & (int)msk;          // masked e (bf16 pair) for l
            union { int i; float f; } lo, hi;
            lo.i = me << 16;
            hi.i = me & (int)0xffff0000u;
            l += lo.f + hi.f;
        }
        const unsigned short* Gb = &Gbuf[b3][lane * 8];
#pragma unroll
        for (int nb = 0; nb < 16; nb++) {
            bf16x8 bfq = *(const bf16x8*)(Gb + nb * 512);
            acc[nb] = __builtin_amdgcn_mfma_f32_16x16x32_bf16(af, bfq, acc[nb], 0, 0, 0);
        }
        __builtin_amdgcn_s_waitcnt(WAIT_LGKM0);  // ds_reads retired before signal
        if (lane == 0) atomicAdd(&vcons[b3], 1);
        A0c = A0n; A1c = A1n;
    }

    // partial l per row m: reduce over q
    l += __shfl_xor(l, 16, 64);
    l += __shfl_xor(l, 32, 64);
    int half = slice * 2 + jh;
    if (lane < 16)
        lbuf[half * N_ + i0b + w * 16 + lane] = l;

    // unnormalized accU (bf16): row = i0b + w*16 + q*4 + reg, col = nb*16 + m
    unsigned short* ob = aggU + ((size_t)half * N_ + i0b + w * 16 + q * 4) * DOUT + m;
#pragma unroll
    for (int nb = 0; nb < 16; nb++) {
#pragma unroll
        for (int reg = 0; reg < 4; reg++)
            ob[(size_t)reg * DOUT + nb * 16] = f2bf(acc[nb][reg]);
    }
}

// ---- k4: combine halves, gate, write out ------------------------------------
__global__ __launch_bounds__(256) void k4_out(const unsigned short* __restrict__ aggU,
        const float* __restrict__ lbuf, const float* __restrict__ gate_w,
        const float* __restrict__ gate_b, float* __restrict__ out) {
    __shared__ float red[4];
    int bid = blockIdx.x;  // 8192 = b*1024 + n
    int n = bid & 1023, b = bid >> 10;
    int d = threadIdx.x;
    float s = 0.f;
#pragma unroll
    for (int r = 0; r < R_; r++) {
        int sl = b * R_ + r;
        float a0 = bf2f(aggU[((size_t)(sl * 2 + 0) * N_ + n) * DOUT + d]);
        float a1 = bf2f(aggU[((size_t)(sl * 2 + 1) * N_ + n) * DOUT + d]);
        float lt = lbuf[(sl * 2 + 0) * N_ + n] + lbuf[(sl * 2 + 1) * N_ + n];
        float inv = (lt > 0.f) ? 1.0f / lt : 0.f;
        s += (a0 + a1) * inv;
    }
    float v = s * gate_w[d];
#pragma unroll
    for (int off = 32; off; off >>= 1) v += __shfl_down(v, off, 64);
    int lane = d & 63, wave = d >> 6;
    if (lane == 0) red[wave] = v;
    __syncthreads();
    float tot = red[0] + red[1] + red[2] + red[3];
    float g = 1.f / (1.f + __expf(-(tot + gate_b[0])));
    out[((long)(b * N_ + n)) * DOUT + d] = g * s;
}

extern "C" void kernel_launch(void* const* d_in, const int* in_sizes, int n_in,
                              void* d_out, int out_size, void* d_ws, size_t ws_size,
                              hipStream_t stream) {
    const float* node   = (const float*)d_in[0];
    const int*   adj    = (const int*)d_in[1];
    const float* rel_w  = (const float*)d_in[2];
    const float* rel_b  = (const float*)d_in[3];
    const float* attn_w = (const float*)d_in[4];
    // d_in[5] = attn_b: cancels in softmax, unused
    const float* gate_w = (const float*)d_in[6];
    const float* gate_b = (const float*)d_in[7];
    float* out = (float*)d_out;

    char* ws = (char*)d_ws;
    unsigned short* swzW = (unsigned short*)ws;                        // 524,288 B
    unsigned short* fswz = (unsigned short*)(ws + 524288);             // 16,777,216 B (G)
    unsigned short* ebf  = (unsigned short*)(ws + 17301504);           // 65,536 B
    unsigned short* aggU = (unsigned short*)(ws + 17367040);           // 33,554,432 B (bf16)
    float*          lbuf = (float*)(ws + 50921472);                    // 262,144 B

    k0_swz<<<128, 256, 0, stream>>>(rel_w, swzW);
    k1_proj<<<512, 256, 0, stream>>>(node, swzW, rel_b, attn_w, fswz, ebf);
    k3_attn<<<1024, 320, 0, stream>>>(adj, fswz, ebf, aggU, lbuf);
    k4_out<<<8192, 256, 0, stream>>>(aggU, lbuf, gate_w, gate_b, out);
}